// Round 16
// baseline (41.178 us; speedup 1.0000x reference)
//
#include <hip/hip_runtime.h>

#define NF   784
#define ZD   64
#define BXN  256
#define BZN  4096
#define KDIM 3136    // 4*NF
#define LCOL 1568    // 2*NF logit columns

typedef __attribute__((ext_vector_type(8))) short bf16x8;
typedef __attribute__((ext_vector_type(4))) float f32x4;
typedef __attribute__((ext_vector_type(8))) unsigned short ushort8;
typedef __attribute__((ext_vector_type(4))) unsigned short us4;   // clang vector: nontemporal-ok

__device__ __forceinline__ unsigned short f2bf(float f) {
  unsigned u = __float_as_uint(f);
  u += 0x7fff + ((u >> 16) & 1);   // round-to-nearest-even
  return (unsigned short)(u >> 16);
}

// v_cvt_pk_bf16_f32: pack 2 f32 -> 2 bf16 (RNE) in one VALU op (no builtin; m240)
__device__ __forceinline__ unsigned pkbf(float a, float b) {
  unsigned r;
  asm("v_cvt_pk_bf16_f32 %0, %1, %2" : "=v"(r) : "v"(a), "v"(b));
  return r;
}

// ---------------- Kernel 1: prep (build_a + W transpose) ----------------
__global__ __launch_bounds__(256) void prep(const float* __restrict__ x,
                                            const float* __restrict__ W,
                                            const int* __restrict__ tree,
                                            unsigned short* __restrict__ Amat,
                                            unsigned short* __restrict__ Wt) {
  int bid = blockIdx.x, tid = threadIdx.x;
  if (bid < 1024) {                       // ---- build_a
    int b = bid >> 2;
    int j = (bid & 3) * 256 + tid;
    if (j >= NF) return;
    float xb = x[b * NF + j];
    int idx = tree[j];
    int gidx = idx < 0 ? idx + NF : idx;  // JAX negative-index wrap
    float xt = x[b * NF + gidx];
    ushort4 v;
    v.x = f2bf((1.f - xt) * xb);
    v.y = f2bf(xt * xb);
    v.z = f2bf((1.f - xt) * (1.f - xb));
    v.w = f2bf(xt * (1.f - xb));
    *(ushort4*)&Amat[(size_t)b * KDIM + 4 * j] = v;
  } else {                                // ---- W -> Wt (transpose), 98 blocks
    int t = (bid - 1024) * 256 + tid;     // 0..25087
    int c = t >> 4, k0 = (t & 15) * 4;
    ushort4 o;
    o.x = f2bf(W[(k0 + 0) * LCOL + c]);
    o.y = f2bf(W[(k0 + 1) * LCOL + c]);
    o.z = f2bf(W[(k0 + 2) * LCOL + c]);
    o.w = f2bf(W[(k0 + 3) * LCOL + c]);
    *(ushort4*)&Wt[c * 64 + k0] = o;
  }
}

// ---------------- Kernel 2: FUSED logits+logsigmoid+GEMM, 8-wave blocks ----------------
// 512 blocks (64 nt x 8 ks) x 512 thr (8 waves) -> 2 blocks/CU = 4 waves/SIMD (2x R15 TLP).
// Waves 0-3 produce the 64-row logit tile ONCE (wave-uniform if(w<4)); all 8 waves
// stage A (256x32 LDS tile) and compute 32 output rows each (acc[2][4]).
#define LP 40
__global__ __launch_bounds__(512, 4) void gemm_fused(const unsigned short* __restrict__ Amat,
                                                     const float* __restrict__ z,
                                                     const unsigned short* __restrict__ Wt,
                                                     const float* __restrict__ bias,
                                                     const int* __restrict__ tree,
                                                     unsigned short* __restrict__ part) {
  __shared__ unsigned short As[2][256][LP];  // 40960 B
  __shared__ unsigned short Bs[2][64][LP];   // 10240 B
  int bid = blockIdx.x;                      // 512 = 64 n-tiles x 8 k-splits
  int s = bid & 7, nt = bid >> 3;
  int n0 = nt * 64;
  int kt0 = s * 12 + (s < 2 ? s : 2);        // 98 = 13+13+12*6
  int nsteps = (s < 2) ? 13 : 12;
  int ktend = kt0 + nsteps;
  int tid = threadIdx.x;
  int w = tid >> 6, lane = tid & 63;
  int fr = lane & 15, hi = lane >> 4, kq = hi * 8;
  int srow = tid >> 1, scol = (tid & 1) * 8;         // A staging: 2 x 16B per thread
  const unsigned short* Ag = Amat + (size_t)srow * KDIM + scol;
  bool prod = (w < 4);                               // logit-producer waves

  // z fragments: producer wave's 16 z-rows, packed f32->bf16 in-register.
  bf16x8 zf0 = {}, zf1 = {};
  if (prod) {
    const float* zpf = z + (size_t)(n0 + w * 16 + fr) * 64 + kq;
    float4 zl0 = *(const float4*)(zpf);
    float4 zl1 = *(const float4*)(zpf + 4);
    float4 zl2 = *(const float4*)(zpf + 32);
    float4 zl3 = *(const float4*)(zpf + 36);
    union { unsigned u[4]; bf16x8 v; } Z0, Z1;
    Z0.u[0] = pkbf(zl0.x, zl0.y); Z0.u[1] = pkbf(zl0.z, zl0.w);
    Z0.u[2] = pkbf(zl1.x, zl1.y); Z0.u[3] = pkbf(zl1.z, zl1.w);
    Z1.u[0] = pkbf(zl2.x, zl2.y); Z1.u[1] = pkbf(zl2.z, zl2.w);
    Z1.u[2] = pkbf(zl3.x, zl3.y); Z1.u[3] = pkbf(zl3.z, zl3.w);
    zf0 = Z0.v; zf1 = Z1.v;
  }

  f32x4 acc[2][4];
#pragma unroll
  for (int m = 0; m < 2; ++m)
#pragma unroll
    for (int n = 0; n < 4; ++n) acc[m][n] = (f32x4){0.f, 0.f, 0.f, 0.f};

  // ---- prologue: load step kt0's registers
  bf16x8 wf0 = {}, wf1 = {};
  float4 b4 = {};
  int2 tr2 = {};
  if (prod) {
    const unsigned short* wp = Wt + (size_t)(kt0 * 16 + fr) * 64 + kq;
    wf0 = *(const bf16x8*)wp;
    wf1 = *(const bf16x8*)(wp + 32);
    b4  = *(const float4*)&bias[kt0 * 16 + 4 * hi];
    tr2 = *(const int2*)&tree[kt0 * 8 + 2 * hi];
  }
  int k0 = kt0 * 32;
  float4 ar0 = *(const float4*)(Ag + k0);
  float4 ar1 = *(const float4*)(Ag + 16 + k0);

  int buf = 0;
  for (int i = 0; i < nsteps; ++i) {
    int kt = kt0 + i;
    int ktn = (kt + 1 < ktend) ? kt + 1 : kt;
    // --- 1. logit MFMA (producer waves; operands already in regs)
    f32x4 lacc = (f32x4){0.f, 0.f, 0.f, 0.f};
    if (prod) {
      lacc = __builtin_amdgcn_mfma_f32_16x16x32_bf16(wf0, zf0, lacc, 0, 0, 0);
      lacc = __builtin_amdgcn_mfma_f32_16x16x32_bf16(wf1, zf1, lacc, 0, 0, 0);
    }
    // --- 2. prefetch step kt+1 (A: all waves; W/bias/tree: producers)
    bf16x8 wfn0 = {}, wfn1 = {};
    float4 b4n = {};
    int2 tr2n = {};
    if (prod) {
      const unsigned short* wpn = Wt + (size_t)(ktn * 16 + fr) * 64 + kq;
      wfn0 = *(const bf16x8*)wpn;
      wfn1 = *(const bf16x8*)(wpn + 32);
      b4n  = *(const float4*)&bias[ktn * 16 + 4 * hi];
      tr2n = *(const int2*)&tree[ktn * 8 + 2 * hi];
    }
    int k0n = ktn * 32;
    float4 arn0 = *(const float4*)(Ag + k0n);
    float4 arn1 = *(const float4*)(Ag + 16 + k0n);
    // --- 3. log-sigmoid epilogue + Bs write (producer waves)
    if (prod) {
      float bb[4] = { b4.x, b4.y, b4.z, b4.w };
      int tt[2] = { tr2.x, tr2.y };
      union { unsigned u[4]; ushort8 v; } V;
#pragma unroll
      for (int p = 0; p < 2; ++p) {
        float l1 = lacc[2 * p + 1] + bb[2 * p + 1];
        float l0 = (tt[p] == -1) ? l1 : (lacc[2 * p] + bb[2 * p]);
        // logsig(v) = v>=0 ? -log(1+e^-v) : v - log(1+e^v);  logsig(-v) = logsig(v) - v
        float e0 = __expf(-fabsf(l0)); float sp0 = __logf(1.f + e0);
        float ls0 = (l0 >= 0.f) ? -sp0 : l0 - sp0;
        float e1 = __expf(-fabsf(l1)); float sp1 = __logf(1.f + e1);
        float ls1 = (l1 >= 0.f) ? -sp1 : l1 - sp1;
        V.u[2 * p + 0] = pkbf(ls0, ls1);           // [ls0, ls1]
        V.u[2 * p + 1] = pkbf(ls0 - l0, ls1 - l1); // [lsn0, lsn1]
      }
      *(ushort8*)&Bs[buf][w * 16 + fr][kq] = V.v;
    }
    // --- 4. stage A to LDS[buf] (all waves)
    *(float4*)&As[buf][srow][scol     ] = ar0;
    *(float4*)&As[buf][srow][scol + 16] = ar1;
    __syncthreads();          // single barrier: dbuf makes write(k+1) race-free
    // --- 5. main MFMA: 8 per wave (2m x 4n), wave w owns rows [32w, 32w+32)
    bf16x8 a0 = *(const bf16x8*)&As[buf][w * 32 + fr][kq];
    bf16x8 a1 = *(const bf16x8*)&As[buf][w * 32 + 16 + fr][kq];
    bf16x8 b[4];
#pragma unroll
    for (int n = 0; n < 4; ++n) b[n] = *(const bf16x8*)&Bs[buf][n * 16 + fr][kq];
#pragma unroll
    for (int n = 0; n < 4; ++n) {
      acc[0][n] = __builtin_amdgcn_mfma_f32_16x16x32_bf16(a0, b[n], acc[0][n], 0, 0, 0);
      acc[1][n] = __builtin_amdgcn_mfma_f32_16x16x32_bf16(a1, b[n], acc[1][n], 0, 0, 0);
    }
    // --- 6. rotate pipeline registers
    wf0 = wfn0; wf1 = wfn1; b4 = b4n; tr2 = tr2n;
    ar0 = arn0; ar1 = arn1;
    buf ^= 1;
  }
  // C/D: col = lane&15 (n), row = (lane>>4)*4 + reg (m). bf16 partials, nt stores.
  int col = lane & 15, rq = hi * 4;
  unsigned short* Pp = part + (size_t)s * (256 * 4096) + (size_t)(w * 32) * 4096 + n0;
#pragma unroll
  for (int m = 0; m < 2; ++m)
#pragma unroll
    for (int n = 0; n < 4; ++n)
#pragma unroll
      for (int r = 0; r < 4; ++r)
        __builtin_nontemporal_store(f2bf(acc[m][n][r]),
                                    &Pp[(m * 16 + rq + r) * 4096 + n * 16 + col]);
}

// ---------------- Kernel 3: reduce 8 bf16 partials -> f32 d_out ----------------
__global__ __launch_bounds__(256) void reduce8(const unsigned short* __restrict__ part,
                                               float* __restrict__ out) {
  int t = blockIdx.x * 256 + threadIdx.x;  // 262144 threads x 4 cols
  f32x4 s = (f32x4){0.f, 0.f, 0.f, 0.f};
#pragma unroll
  for (int q = 0; q < 8; ++q) {
    const us4* p = (const us4*)&part[(size_t)q * (256 * 4096) + (size_t)t * 4];
    us4 v = __builtin_nontemporal_load(p);
    s[0] += __uint_as_float((unsigned)v[0] << 16);
    s[1] += __uint_as_float((unsigned)v[1] << 16);
    s[2] += __uint_as_float((unsigned)v[2] << 16);
    s[3] += __uint_as_float((unsigned)v[3] << 16);
  }
  f32x4* o = (f32x4*)&out[(size_t)t * 4];
  __builtin_nontemporal_store(s, o);
}

extern "C" void kernel_launch(void* const* d_in, const int* in_sizes, int n_in,
                              void* d_out, int out_size, void* d_ws, size_t ws_size,
                              hipStream_t stream) {
  const float* x    = (const float*)d_in[0];
  const float* z    = (const float*)d_in[1];
  const float* W    = (const float*)d_in[2];
  const float* bias = (const float*)d_in[3];
  const int*   tree = (const int*)d_in[4];
  float* out = (float*)d_out;

  unsigned short* Amat = (unsigned short*)d_ws;                     //  1,605,632 B
  unsigned short* Wt   = (unsigned short*)((char*)d_ws + 1605632);  //    200,704 B
  unsigned short* part = (unsigned short*)((char*)d_ws + 1806336);  // 16,777,216 B (bf16)

  prep<<<dim3(1122), 256, 0, stream>>>(x, W, tree, Amat, Wt);
  gemm_fused<<<dim3(512), 512, 0, stream>>>(Amat, z, Wt, bias, tree, part);
  reduce8<<<dim3(1024), 256, 0, stream>>>(part, out);
}